// Round 1
// 403.664 us; speedup vs baseline: 1.3184x; 1.3184x over previous
//
#include <hip/hip_runtime.h>
#include <hip/hip_bf16.h>
#include <stdint.h>

// ---------------------------------------------------------------------------
// AdaptiveDecision fused kernel, MI355X / gfx950  (round 3)
//
// Math (per row, B=32768, C=1024, CH=256):
//   h  = LN(x); d = h@Wd+bd; g = h@Wg+bg; h1 = d*sigmoid(g)
//   h1 = h1*dw_w + dw_b                      (folded into W1)
//   t  = gelu_tanh(h1@W1'+b1')
//   y  = t@Wcomb + bcomb                     (Wcomb = W2@Wv@Wo@Wu@(I+Wld@Wlu))
//   out= 0.5*y + 0.5*x
// LN folding: LN(x)@W = rs*(x@(g.*W)) - rs*mu*colsum(g.*W) + (b + ln_b@W)
// Bias chain rides as row 256 of a 272-row A through the weight-chain GEMMs.
//
// Round-3 change: the old k_packwc (9 blocks, 139.7us, 0.35% occupancy —
// the top dispatch in rocprof) is replaced by two wide kernels:
//   k_lora_m4  (257 blocks): M4[257x16] = M3rows @ Wld
//   k_packwc2  (65 blocks):  PWc tile-parallel pack of M3 + M4@Wlu; bcomb
// ---------------------------------------------------------------------------

typedef float f32x4 __attribute__((ext_vector_type(4)));
typedef __bf16 bf16x8 __attribute__((ext_vector_type(8)));
typedef unsigned short u16x8 __attribute__((ext_vector_type(8)));
typedef unsigned short u16x4 __attribute__((ext_vector_type(4)));

#define LN_EPS 1e-5f

__device__ __forceinline__ unsigned short f2bf(float f) {
  unsigned int u = __float_as_uint(f);
  u += 0x7fffu + ((u >> 16) & 1u);          // RNE
  return (unsigned short)(u >> 16);
}

// barrier that does NOT drain vmcnt: LDS-visibility only. Keeps prefetched
// global loads in flight across the barrier (the __syncthreads vmcnt(0) drain
// was the round-1 stall).
__device__ __forceinline__ void bar_lds() {
  asm volatile("s_waitcnt lgkmcnt(0)\n\ts_barrier" ::: "memory");
}

// ---------------------------------------------------------------------------
// P1: all independent prep in one launch (138 blocks):
//  0-31  : pack ln_g.*Wd -> PGd (+ atomic colsums gdvA, bdA)
//  32-63 : pack ln_g.*Wg -> PGg (+ atomic colsums ggvA, bgA)
//  64-71 : pack dw_w.*W1 -> PW1
//  72-79 : pack Wv -> PWv ; 80-87: Wo -> PWo ; 88-119: Wu -> PWu (N=1024)
//  120   : b1p = b1 + dw_b@W1
//  121-137: build A0 = [W2; b2; zeros]  (272 x 256 fp32)
// Packed B-frag layout: P[((kc*NT+nt)*64+lane)*8+j] = W[kc*32+(lane>>4)*8+j][nt*16+(lane&15)]
// ---------------------------------------------------------------------------
__global__ __launch_bounds__(256) void k_prep1(
    const float* __restrict__ ln_g, const float* __restrict__ ln_b,
    const float* __restrict__ Wd, const float* __restrict__ Wg,
    const float* __restrict__ dw_w, const float* __restrict__ dw_b,
    const float* __restrict__ W1, const float* __restrict__ b1,
    const float* __restrict__ W2, const float* __restrict__ b2,
    const float* __restrict__ Wv, const float* __restrict__ Wo,
    const float* __restrict__ Wu,
    unsigned short* __restrict__ PGd, unsigned short* __restrict__ PGg,
    unsigned short* __restrict__ PW1, unsigned short* __restrict__ PWv,
    unsigned short* __restrict__ PWo, unsigned short* __restrict__ PWu,
    float* __restrict__ gdvA, float* __restrict__ ggvA,
    float* __restrict__ bdA, float* __restrict__ bgA,
    float* __restrict__ b1p, float* __restrict__ A0) {
  __shared__ float S[32][257];
  const int b = blockIdx.x, tid = threadIdx.x;

  if (b < 120) {
    const float* src; const float* scale = nullptr; unsigned short* dst;
    int N = 256, kc, NT = 16, nt0 = 0;
    bool csum = false; float* accg_ = nullptr; float* accb_ = nullptr;
    if (b < 32)      { src = Wd; scale = ln_g; dst = PGd; kc = b;      csum = true; accg_ = gdvA; accb_ = bdA; }
    else if (b < 64) { src = Wg; scale = ln_g; dst = PGg; kc = b - 32; csum = true; accg_ = ggvA; accb_ = bgA; }
    else if (b < 72) { src = W1; scale = dw_w; dst = PW1; kc = b - 64; }
    else if (b < 80) { src = Wv; dst = PWv; kc = b - 72; }
    else if (b < 88) { src = Wo; dst = PWo; kc = b - 80; }
    else { int idx = b - 88; kc = idx >> 2; nt0 = (idx & 3) * 16; src = Wu; dst = PWu; N = 1024; NT = 64; }
    const int n0 = nt0 * 16;
    float csg = 0.f, csb = 0.f;
    for (int r = 0; r < 32; ++r) {
      int k = kc * 32 + r;
      float raw = src[(size_t)k * N + n0 + tid];
      float v = scale ? scale[k] * raw : raw;
      S[r][tid] = v;
      if (csum) { csg += v; csb += ln_b[k] * raw; }
    }
    if (csum) { atomicAdd(&accg_[tid], csg); atomicAdd(&accb_[tid], csb); }
    __syncthreads();
    const int ntL = tid >> 4;
    #pragma unroll
    for (int c = 0; c < 4; ++c) {
      int lane = (tid * 4 + c) & 63;
      int kb = (lane >> 4) * 8, nl = ntL * 16 + (lane & 15);
      u16x8 o;
      #pragma unroll
      for (int j = 0; j < 8; ++j) o[j] = f2bf(S[kb + j][nl]);
      *(u16x8*)(dst + ((size_t)(kc * NT + nt0 + ntL) * 64 + lane) * 8) = o;
    }
  } else if (b == 120) {
    float s = 0.f;
    for (int k = 0; k < 256; ++k) s += dw_b[k] * W1[k * 256 + tid];
    b1p[tid] = b1[tid] + s;
  } else {
    int rb = b - 121;                       // 0..16
    for (int it = 0; it < 16; ++it) {
      int el = rb * 4096 + it * 256 + tid;  // < 272*256
      int row = el >> 8, col = el & 255;
      float v = (row < 256) ? W2[el] : ((row == 256) ? b2[col] : 0.f);
      A0[el] = v;
    }
  }
}

// ---------------------------------------------------------------------------
// Chain GEMM: C[272,N] = A[272,256] @ PB(packed bf16), bias added to row 256.
// grid (17, N/256), 256 threads (4 waves), 16 rows/block, MFMA 16x16x32.
// ---------------------------------------------------------------------------
__global__ __launch_bounds__(256) void k_gemm272(
    const float* __restrict__ A, const unsigned short* __restrict__ PB,
    float* __restrict__ C, const float* __restrict__ bias, int NT) {
  __shared__ unsigned short XA[512];
  const int tid = threadIdx.x;
  const int w = tid >> 6, l = tid & 63, q = l >> 4, m15 = l & 15;
  const int r0 = blockIdx.x * 16, ncg = blockIdx.y, N = NT * 16;

  const int srow = tid >> 4, kk = (tid & 15) * 2;
  const int xaidx = ((kk >> 3) * 16 + srow) * 8 + (kk & 7);
  const float* arow = A + (size_t)(r0 + srow) * 256 + kk;

  f32x4 acc[4];
  const f32x4 zero4 = {0.f, 0.f, 0.f, 0.f};
  #pragma unroll
  for (int i = 0; i < 4; ++i) acc[i] = zero4;

  for (int kc = 0; kc < 8; ++kc) {
    float2 v = *(const float2*)(arow + kc * 32);
    u16x4 hv; hv[0] = f2bf(v.x); hv[1] = f2bf(v.y); hv[2] = 0; hv[3] = 0;
    XA[xaidx] = hv[0]; XA[xaidx + 1] = hv[1];
    __syncthreads();
    bf16x8 af = *(const bf16x8*)&XA[l * 8];
    #pragma unroll
    for (int i = 0; i < 4; ++i) {
      bf16x8 bf = *(const bf16x8*)(PB + ((size_t)(kc * NT + ncg * 16 + w * 4 + i) * 64 + l) * 8);
      acc[i] = __builtin_amdgcn_mfma_f32_16x16x32_bf16(af, bf, acc[i], 0, 0, 0);
    }
    __syncthreads();
  }
  #pragma unroll
  for (int i = 0; i < 4; ++i) {
    int col = ncg * 256 + (w * 4 + i) * 16 + m15;
    #pragma unroll
    for (int r = 0; r < 4; ++r) {
      int grow = r0 + q * 4 + r;
      float v = acc[i][r];
      if (grow == 256) v += bias[col];
      C[(size_t)grow * N + col] = v;
    }
  }
}

// ---------------------------------------------------------------------------
// P5a: M4[257x16] = M3[rows 0..256] @ Wld.  One block per row, 256 threads.
// Each thread: 4 strided M3 elements (coalesced) x 16 contiguous Wld cols.
// Two-stage LDS reduction. Replaces the serial 1024-dot loops of old packwc.
// ---------------------------------------------------------------------------
__global__ __launch_bounds__(256) void k_lora_m4(
    const float* __restrict__ M3, const float* __restrict__ Wld,
    float* __restrict__ M4) {
  __shared__ float RED[256 * 16];   // 16KB
  __shared__ float RED2[16 * 16];
  const int r = blockIdx.x, tid = threadIdx.x;
  const float* mrow = M3 + (size_t)r * 1024;
  float p[16];
  #pragma unroll
  for (int c = 0; c < 16; ++c) p[c] = 0.f;
  #pragma unroll
  for (int k = 0; k < 4; ++k) {
    int n = tid + k * 256;
    float m = mrow[n];
    const float* wl = Wld + n * 16;
    #pragma unroll
    for (int c = 0; c < 16; ++c) p[c] += m * wl[c];
  }
  #pragma unroll
  for (int c = 0; c < 16; ++c) RED[tid * 16 + c] = p[c];
  __syncthreads();
  {
    const int c = tid & 15, g = tid >> 4;   // 16 groups x 16 cols
    float s = 0.f;
    #pragma unroll
    for (int i = 0; i < 16; ++i) s += RED[(g * 16 + i) * 16 + c];
    RED2[g * 16 + c] = s;
  }
  __syncthreads();
  if (tid < 16) {
    float s = 0.f;
    #pragma unroll
    for (int g = 0; g < 16; ++g) s += RED2[g * 16 + tid];
    M4[r * 16 + tid] = s;
  }
}

// ---------------------------------------------------------------------------
// P5b: blocks 0..63: tile-parallel PWc = pack_bf16(M3 + M4@Wlu).
//   block b -> rows kc*32..+32 (kc=b>>3), cols ccol..ccol+128 (ccol=(b&7)*128)
//   Wlu chunk + M4 slab staged in LDS; T computed in registers.
// block 64: bcomb = bc3 + M4[row 256]@Wlu.
// ---------------------------------------------------------------------------
__global__ __launch_bounds__(256) void k_packwc2(
    const float* __restrict__ M3, const float* __restrict__ M4,
    const float* __restrict__ Wlu, unsigned short* __restrict__ PWc,
    float* __restrict__ bcomb) {
  const int b = blockIdx.x, tid = threadIdx.x;
  if (b < 64) {
    __shared__ float M4L[32 * 16];            // 2KB
    __shared__ float WL[16 * 128];            // 8KB
    __shared__ unsigned short TL[32 * 132];   // 8.25KB (pad 128->132)
    const int kc = b >> 3, ccol = (b & 7) * 128;
    // load M4 slab (32 rows x 16 = 512 floats)
    M4L[tid] = M4[(size_t)kc * 512 + tid];
    M4L[tid + 256] = M4[(size_t)kc * 512 + 256 + tid];
    // load Wlu chunk [16][128]
    #pragma unroll
    for (int i = 0; i < 8; ++i) {
      int el = tid + i * 256;                 // 0..2047
      int s = el >> 7, n = el & 127;
      WL[el] = Wlu[(size_t)s * 1024 + ccol + n];
    }
    __syncthreads();
    // compute T: thread -> row r=tid>>3, cols c0=(tid&7)*16 .. +15
    const int r = tid >> 3, c0 = (tid & 7) * 16;
    const float* mrow = M3 + (size_t)(kc * 32 + r) * 1024 + ccol + c0;
    float acc[16];
    #pragma unroll
    for (int c = 0; c < 16; ++c) acc[c] = mrow[c];
    #pragma unroll
    for (int s = 0; s < 16; ++s) {
      float m = M4L[r * 16 + s];
      #pragma unroll
      for (int c = 0; c < 16; ++c) acc[c] += m * WL[s * 128 + c0 + c];
    }
    #pragma unroll
    for (int c = 0; c < 16; ++c) TL[r * 132 + c0 + c] = f2bf(acc[c]);
    __syncthreads();
    // pack: thread -> ntL = tid>>5 (0..7), two lanes (tid&31) and +32
    const int ntL = tid >> 5;
    #pragma unroll
    for (int hlf = 0; hlf < 2; ++hlf) {
      int lane = (tid & 31) + hlf * 32;
      int kb = (lane >> 4) * 8, nl = ntL * 16 + (lane & 15);
      u16x8 o;
      #pragma unroll
      for (int j = 0; j < 8; ++j) o[j] = TL[(kb + j) * 132 + nl];
      *(u16x8*)(PWc + ((size_t)(kc * 64 + (b & 7) * 8 + ntL) * 64 + lane) * 8) = o;
    }
  } else {
    __shared__ float s16[16];
    if (tid < 16) s16[tid] = M4[256 * 16 + tid];
    __syncthreads();
    const float* bc3 = M3 + (size_t)256 * 1024;
    #pragma unroll
    for (int c = 0; c < 4; ++c) {
      int n = tid + c * 256;
      float v = bc3[n];
      #pragma unroll
      for (int s = 0; s < 16; ++s) v += s16[s] * Wlu[s * 1024 + n];
      bcomb[n] = v;
    }
  }
}

// ---------------------------------------------------------------------------
// Main fused kernel. 512 blocks x 512 threads (8 waves), 64 rows/block.
// Frag layouts (verified round 1): A[m=lane&15][k=(lane>>4)*8+j],
// B[k=(lane>>4)*8+j][n=lane&15], D[row=(lane>>4)*4+r][col=lane&15]
// ---------------------------------------------------------------------------
__global__ __launch_bounds__(512, 4) void k_main(
    const float* __restrict__ x,
    const unsigned short* __restrict__ PGd, const unsigned short* __restrict__ PGg,
    const unsigned short* __restrict__ PW1, const unsigned short* __restrict__ PWc,
    const float* __restrict__ gdvA, const float* __restrict__ ggvA,
    const float* __restrict__ bdA, const float* __restrict__ bgA,
    const float* __restrict__ bd, const float* __restrict__ bg,
    const float* __restrict__ b1p, const float* __restrict__ bcomb,
    float* __restrict__ out) {
  __shared__ unsigned short XA[2][2048];       // 8KB  dbuf A-frag staging
  __shared__ unsigned short HBUF[16384];       // 32KB h1 / t as A-frags
  __shared__ float SMS[1024];                  // 4KB  LN partials
  __shared__ float MURS[128];                  // mu, rs per row
  __shared__ float OBUF[16 * 260];             // 16.6KB output staging tile

  const int tid = threadIdx.x;
  const int w = tid >> 6, l = tid & 63, q = l >> 4, m15 = l & 15;
  const int row0 = blockIdx.x * 64;

  float gdc[2], ggc[2], bdc[2], bgc[2], b1c[2];
  #pragma unroll
  for (int i = 0; i < 2; ++i) {
    int col = w * 32 + i * 16 + m15;
    gdc[i] = gdvA[col]; ggc[i] = ggvA[col];
    bdc[i] = bdA[col] + bd[col];
    bgc[i] = bgA[col] + bg[col];
    b1c[i] = b1p[col];
  }

  // ---------------- stage 1: [64,1024] @ (Gd|Gg) ------------------------------
  f32x4 accd[4][2], accg[4][2];
  const f32x4 zero4 = {0.f, 0.f, 0.f, 0.f};
  #pragma unroll
  for (int mt = 0; mt < 4; ++mt)
    #pragma unroll
    for (int i = 0; i < 2; ++i) { accd[mt][i] = zero4; accg[mt][i] = zero4; }

  const int srow = tid >> 3, sseg = tid & 7;
  const float* xrow = x + (size_t)(row0 + srow) * 1024 + sseg * 4;
  const int xaidx = (((srow >> 4) * 64 + (sseg >> 1) * 16 + (srow & 15)) << 3) + (sseg & 1) * 4;
  float ssum = 0.f, ssq = 0.f;

  float4 v = *(const float4*)xrow;
  for (int kc = 0; kc < 32; ++kc) {
    const int p = kc & 1;
    u16x4 hv; hv[0] = f2bf(v.x); hv[1] = f2bf(v.y); hv[2] = f2bf(v.z); hv[3] = f2bf(v.w);
    *(u16x4*)&XA[p][xaidx] = hv;
    ssum += v.x + v.y + v.z + v.w;
    ssq += v.x * v.x + v.y * v.y + v.z * v.z + v.w * v.w;
    if (kc < 31) v = *(const float4*)(xrow + (kc + 1) * 32);   // prefetch (survives bar_lds)
    bar_lds();
    bf16x8 fd[2], fg[2];
    #pragma unroll
    for (int i = 0; i < 2; ++i) {
      size_t off = ((size_t)(kc * 16 + w * 2 + i) * 64 + l) * 8;
      fd[i] = *(const bf16x8*)(PGd + off);
      fg[i] = *(const bf16x8*)(PGg + off);
    }
    #pragma unroll
    for (int mt = 0; mt < 4; ++mt) {
      bf16x8 af = *(const bf16x8*)&XA[p][(mt * 64 + l) * 8];
      #pragma unroll
      for (int i = 0; i < 2; ++i) {
        accd[mt][i] = __builtin_amdgcn_mfma_f32_16x16x32_bf16(af, fd[i], accd[mt][i], 0, 0, 0);
        accg[mt][i] = __builtin_amdgcn_mfma_f32_16x16x32_bf16(af, fg[i], accg[mt][i], 0, 0, 0);
      }
    }
  }

  // LN statistics (8 partials/row)
  SMS[tid] = ssum;
  SMS[512 + tid] = ssq;
  bar_lds();
  if (tid < 64) {
    float s = 0.f, sq = 0.f;
    #pragma unroll
    for (int p2 = 0; p2 < 8; ++p2) { s += SMS[tid * 8 + p2]; sq += SMS[512 + tid * 8 + p2]; }
    float mu = s * (1.f / 1024.f);
    float var = sq * (1.f / 1024.f) - mu * mu;
    MURS[tid * 2] = mu;
    MURS[tid * 2 + 1] = rsqrtf(var + LN_EPS);
  }
  bar_lds();

  // stage-1 epilogue: LN correction + GLU gate -> h1 bf16 in HBUF (A-frag order)
  #pragma unroll
  for (int i = 0; i < 2; ++i) {
    int cloc = i * 16 + m15;                 // col = w*32 + cloc ; kc2 = w
    int q2 = i * 2 + (m15 >> 3), j2 = m15 & 7;
    #pragma unroll
    for (int mt = 0; mt < 4; ++mt) {
      #pragma unroll
      for (int r = 0; r < 4; ++r) {
        int row = mt * 16 + q * 4 + r;
        float mu = MURS[row * 2], rs = MURS[row * 2 + 1];
        float pd = rs * (accd[mt][i][r] - mu * gdc[i]) + bdc[i];
        float pg = rs * (accg[mt][i][r] - mu * ggc[i]) + bgc[i];
        float hv = pd / (1.f + __expf(-pg));
        HBUF[((mt * 8 + w) * 64 + q2 * 16 + q * 4 + r) * 8 + j2] = f2bf(hv);
      }
    }
  }
  bar_lds();

  // ---------------- stage 2: t = gelu(h1 @ W1' + b1') ------------------------
  f32x4 acc2[4][2];
  #pragma unroll
  for (int mt = 0; mt < 4; ++mt)
    #pragma unroll
    for (int i = 0; i < 2; ++i) acc2[mt][i] = zero4;
  for (int kc = 0; kc < 8; ++kc) {
    bf16x8 bf[2];
    #pragma unroll
    for (int i = 0; i < 2; ++i)
      bf[i] = *(const bf16x8*)(PW1 + ((size_t)(kc * 16 + w * 2 + i) * 64 + l) * 8);
    #pragma unroll
    for (int mt = 0; mt < 4; ++mt) {
      bf16x8 af = *(const bf16x8*)&HBUF[((mt * 8 + kc) * 64 + l) * 8];
      #pragma unroll
      for (int i = 0; i < 2; ++i)
        acc2[mt][i] = __builtin_amdgcn_mfma_f32_16x16x32_bf16(af, bf[i], acc2[mt][i], 0, 0, 0);
    }
  }
  bar_lds();   // all reads of h1 done before overwrite with t
  #pragma unroll
  for (int i = 0; i < 2; ++i) {
    int q2 = i * 2 + (m15 >> 3), j2 = m15 & 7;
    #pragma unroll
    for (int mt = 0; mt < 4; ++mt) {
      #pragma unroll
      for (int r = 0; r < 4; ++r) {
        float vv = acc2[mt][i][r] + b1c[i];
        float u = 0.7978845608f * (vv + 0.044715f * vv * vv * vv);
        float th = 1.f - 2.f / (1.f + __expf(2.f * u));
        HBUF[((mt * 8 + w) * 64 + q2 * 16 + q * 4 + r) * 8 + j2] = f2bf(0.5f * vv * (1.f + th));
      }
    }
  }
  bar_lds();

  // ---------------- stage 3: y = t @ Wcomb + bcomb; out = 0.5y + 0.5x --------
  for (int nc = 0; nc < 4; ++nc) {
    f32x4 acc3[4][2];
    #pragma unroll
    for (int mt = 0; mt < 4; ++mt)
      #pragma unroll
      for (int i = 0; i < 2; ++i) acc3[mt][i] = zero4;
    for (int kc = 0; kc < 8; ++kc) {
      bf16x8 bf[2];
      #pragma unroll
      for (int i = 0; i < 2; ++i)
        bf[i] = *(const bf16x8*)(PWc + ((size_t)(kc * 64 + nc * 16 + w * 2 + i) * 64 + l) * 8);
      #pragma unroll
      for (int mt = 0; mt < 4; ++mt) {
        bf16x8 af = *(const bf16x8*)&HBUF[((mt * 8 + kc) * 64 + l) * 8];
        #pragma unroll
        for (int i = 0; i < 2; ++i)
          acc3[mt][i] = __builtin_amdgcn_mfma_f32_16x16x32_bf16(af, bf[i], acc3[mt][i], 0, 0, 0);
      }
    }
    float bc[2];
    #pragma unroll
    for (int i = 0; i < 2; ++i) bc[i] = bcomb[nc * 256 + w * 32 + i * 16 + m15];
    // stage through OBUF per 16-row tile for coalesced float4 out writes
    const int rowL = tid >> 5, c0 = (tid & 31) * 4;
    #pragma unroll
    for (int mt = 0; mt < 4; ++mt) {
      #pragma unroll
      for (int r = 0; r < 4; ++r)
        #pragma unroll
        for (int i = 0; i < 2; ++i)
          OBUF[(q * 4 + r) * 260 + w * 32 + i * 16 + m15] = acc3[mt][i][r] + bc[i];
      bar_lds();
      const size_t gbase = (size_t)(row0 + mt * 16 + rowL) * 1024 + nc * 256;
      #pragma unroll
      for (int h = 0; h < 2; ++h) {
        int cc = c0 + h * 128;
        f32x4 yv = *(const f32x4*)&OBUF[rowL * 260 + cc];
        float4 xr = *(const float4*)(x + gbase + cc);
        float4 o;
        o.x = 0.5f * yv[0] + 0.5f * xr.x;
        o.y = 0.5f * yv[1] + 0.5f * xr.y;
        o.z = 0.5f * yv[2] + 0.5f * xr.z;
        o.w = 0.5f * yv[3] + 0.5f * xr.w;
        *(float4*)(out + gbase + cc) = o;
      }
      bar_lds();
    }
  }
}

// ---------------------------------------------------------------------------
extern "C" void kernel_launch(void* const* d_in, const int* in_sizes, int n_in,
                              void* d_out, int out_size, void* d_ws, size_t ws_size,
                              hipStream_t stream) {
  (void)in_sizes; (void)n_in; (void)out_size; (void)ws_size;
  const float* x    = (const float*)d_in[0];
  const float* ln_g = (const float*)d_in[1];
  const float* ln_b = (const float*)d_in[2];
  const float* Wd   = (const float*)d_in[3];
  const float* bd   = (const float*)d_in[4];
  const float* Wg   = (const float*)d_in[5];
  const float* bg   = (const float*)d_in[6];
  const float* dw_w = (const float*)d_in[7];
  const float* dw_b = (const float*)d_in[8];
  const float* W1   = (const float*)d_in[9];
  const float* b1   = (const float*)d_in[10];
  const float* W2   = (const float*)d_in[11];
  const float* b2   = (const float*)d_in[12];
  // d_in[13..16] = Wq,bq,Wk,bk : dead code (softmax over 1 key == 1)
  const float* Wv   = (const float*)d_in[17];
  const float* bv   = (const float*)d_in[18];
  const float* Wo   = (const float*)d_in[19];
  const float* bo   = (const float*)d_in[20];
  const float* Wu   = (const float*)d_in[21];
  const float* bu   = (const float*)d_in[22];
  const float* Wld  = (const float*)d_in[23];
  const float* Wlu  = (const float*)d_in[24];
  float* out = (float*)d_out;

  char* ws = (char*)d_ws;
  unsigned short* PGd = (unsigned short*)(ws + 0);         // 512KB
  unsigned short* PGg = (unsigned short*)(ws + 524288);    // 512KB
  unsigned short* PW1 = (unsigned short*)(ws + 1048576);   // 128KB
  unsigned short* PWv = (unsigned short*)(ws + 1179648);   // 128KB
  unsigned short* PWo = (unsigned short*)(ws + 1310720);   // 128KB
  unsigned short* PWu = (unsigned short*)(ws + 1441792);   // 512KB
  unsigned short* PWc = (unsigned short*)(ws + 1966080);   // 512KB
  float* gdvA  = (float*)(ws + 2490368);                   // 1KB (zeroed)
  float* ggvA  = (float*)(ws + 2491392);                   // 1KB (zeroed)
  float* bdA   = (float*)(ws + 2492416);                   // 1KB (zeroed)
  float* bgA   = (float*)(ws + 2493440);                   // 1KB (zeroed)
  float* b1p   = (float*)(ws + 2494464);                   // 1KB
  float* bcomb = (float*)(ws + 2495488);                   // 4KB
  float* A0    = (float*)(ws + 2499584);                   // 272x256 f32 (278528B)
  float* T1    = (float*)(ws + 2778112);                   // 272x256 f32
  float* T2    = A0;                                       // alias: A0 dead after P2
  float* M3    = T1;                                       // alias: T1 dead after P3
  // M3 is 272x1024 f32 = 1114112B @2778112 -> end 3892224
  // M4 (257x16 f32 = 16448B) reuses the PWv region (dead after chain GEMM #1)
  float* M4    = (float*)(ws + 1179648);

  hipMemsetAsync(ws + 2490368, 0, 4096, stream);
  hipLaunchKernelGGL(k_prep1, dim3(138), dim3(256), 0, stream,
                     ln_g, ln_b, Wd, Wg, dw_w, dw_b, W1, b1, W2, b2, Wv, Wo, Wu,
                     PGd, PGg, PW1, PWv, PWo, PWu, gdvA, ggvA, bdA, bgA, b1p, A0);
  hipLaunchKernelGGL(k_gemm272, dim3(17, 1), dim3(256), 0, stream, A0, PWv, T1, bv, 16);
  hipLaunchKernelGGL(k_gemm272, dim3(17, 1), dim3(256), 0, stream, T1, PWo, T2, bo, 16);
  hipLaunchKernelGGL(k_gemm272, dim3(17, 4), dim3(256), 0, stream, T2, PWu, M3, bu, 64);
  hipLaunchKernelGGL(k_lora_m4, dim3(257), dim3(256), 0, stream, M3, Wld, M4);
  hipLaunchKernelGGL(k_packwc2, dim3(65), dim3(256), 0, stream, M3, M4, Wlu, PWc, bcomb);
  hipLaunchKernelGGL(k_main, dim3(512), dim3(512), 0, stream,
                     x, PGd, PGg, PW1, PWc, gdvA, ggvA, bdA, bgA, bd, bg, b1p, bcomb, out);
}